// Round 6
// baseline (556.620 us; speedup 1.0000x reference)
//
#include <hip/hip_runtime.h>
#include <hip/hip_bf16.h>
#include <hip/hip_cooperative_groups.h>

namespace cg = cooperative_groups;
using bf16 = __hip_bfloat16;

constexpr int N_ = 2048;    // nodes
constexpr int E_ = 4096;    // edges
constexpr int CAP = 64;     // max nnz per adjacency row
constexpr int BT = 65536;   // 256 blocks x 256 threads

__device__ __forceinline__ void unpack8(uint4 u, float* f) {
    unsigned w0 = u.x, w1 = u.y, w2 = u.z, w3 = u.w;
    f[0] = __uint_as_float(w0 << 16); f[1] = __uint_as_float(w0 & 0xffff0000u);
    f[2] = __uint_as_float(w1 << 16); f[3] = __uint_as_float(w1 & 0xffff0000u);
    f[4] = __uint_as_float(w2 << 16); f[5] = __uint_as_float(w2 & 0xffff0000u);
    f[6] = __uint_as_float(w3 << 16); f[7] = __uint_as_float(w3 & 0xffff0000u);
}

__device__ __forceinline__ void load8(const void* p, long long base, int isbf, float* f) {
    if (isbf) {
        uint4 u = *(const uint4*)((const unsigned short*)p + base);
        unpack8(u, f);
    } else {
        const float4* q = (const float4*)((const float*)p + base);
        float4 a = q[0], b = q[1];
        f[0] = a.x; f[1] = a.y; f[2] = a.z; f[3] = a.w;
        f[4] = b.x; f[5] = b.y; f[6] = b.z; f[7] = b.w;
    }
}

__device__ __forceinline__ float wred64(float v) {
#pragma unroll
    for (int m = 1; m < 64; m <<= 1) v += __shfl_xor(v, m);
    return v;
}
__device__ __forceinline__ float wred16(float v) {
#pragma unroll
    for (int m = 1; m < 16; m <<= 1) v += __shfl_xor(v, m);
    return v;
}

// ---- dtype detect: T holds {0,1,2}; f32 stream -> low16 of every u32 is 0
__global__ void k_detect(const unsigned int* __restrict__ t32, int* __restrict__ flag) {
    long long i = (long long)(blockIdx.x * blockDim.x + threadIdx.x) * 4;
    uint4 u = *(const uint4*)(t32 + i);
    if ((u.x | u.y | u.z | u.w) & 0xFFFFu) *flag = 1;
}

// ---- fused extraction + upconvert (one dispatch, block-partitioned)
constexpr int NCONV = 23;
constexpr int CHUNK = 8192;
struct ConvArgs {
    const void* src[NCONV];
    float* dst[NCONV];
    int n[NCONV];
    int first[NCONV];
    unsigned char blk_entry[64];
};

struct ExtractArgs {
    const void* T; const void* adjV; const void* adjE;
    int* dt;
    int* tcnt; int* trows; float* tvals;
    int* avc; int* avj; float* avv;
    int* aec; int* aej; float* aev;
};

__global__ void k_extract_all(ExtractArgs a, ConvArgs ca) {
    int b = blockIdx.x, t = threadIdx.x;
    int isbf = a.dt[1];
    if (b < 4096) {                 // T extraction: N*E = 8.4M elems
        long long base = ((long long)b * 256 + t) * 8;
        float f[8]; load8(a.T, base, isbf, f);
#pragma unroll
        for (int k = 0; k < 8; k++) {
            if (f[k] != 0.f) {
                long long idx = base + k;
                int e = (int)(idx & (E_ - 1));
                int n = (int)(idx >> 12);
                int p = atomicAdd(&a.tcnt[e], 1);
                if (p < 2) { a.trows[e * 2 + p] = n; a.tvals[e * 2 + p] = f[k]; }
            }
        }
    } else if (b < 6144) {          // adjV: N*N
        long long base = ((long long)(b - 4096) * 256 + t) * 8;
        float f[8]; load8(a.adjV, base, isbf, f);
#pragma unroll
        for (int k = 0; k < 8; k++) {
            if (f[k] != 0.f) {
                long long idx = base + k;
                int row = (int)(idx >> 11), col = (int)(idx & (N_ - 1));
                int s = atomicAdd(&a.avc[row], 1);
                if (s < CAP) { a.avj[row * CAP + s] = col; a.avv[row * CAP + s] = f[k]; }
            }
        }
    } else if (b < 14336) {         // adjE: E*E
        long long base = ((long long)(b - 6144) * 256 + t) * 8;
        float f[8]; load8(a.adjE, base, isbf, f);
#pragma unroll
        for (int k = 0; k < 8; k++) {
            if (f[k] != 0.f) {
                long long idx = base + k;
                int row = (int)(idx >> 12), col = (int)(idx & (E_ - 1));
                int s = atomicAdd(&a.aec[row], 1);
                if (s < CAP) { a.aej[row * CAP + s] = col; a.aev[row * CAP + s] = f[k]; }
            }
        }
    } else {                        // upconvert inputs to f32
        int gb = b - 14336;
        int e = ca.blk_entry[gb];
        int off = (gb - ca.first[e]) * CHUNK;
        int n = ca.n[e];
        const void* src = ca.src[e];
        float* dst = ca.dst[e];
        int lim = min(off + CHUNK, n);
        for (int i = off + t * 8; i < lim; i += 256 * 8) {
            float f[8]; load8(src, i, isbf, f);
            float4* d = (float4*)(dst + i);
            d[0] = make_float4(f[0], f[1], f[2], f[3]);
            d[1] = make_float4(f[4], f[5], f[6], f[7]);
        }
    }
}

// ---- the whole 5-layer pipeline: one cooperative kernel, 8 grid syncs
struct PipeArgs {
    int *tcnt, *trows; float* tvals;
    int *avc, *avj; float* avv;
    int *aec, *aej; float* aev;
    int* eav; float* eprod;
    float *avco1, *avco2, *avco3;
    float *aea1, *aea2, *colmax1, *colmax2;
    float *s_n1, *s_n2;
    float *Xf, *Zf;
    float *W1f, *p1f, *b1f, *Wf1f, *g1f, *be1f;
    float *W2f, *p2f, *b2f, *Wf2f, *g2f, *be2f;
    float *W3f, *p3f, *b3f, *W4f, *p4f, *b4f;
    float *W5f, *p5f, *b5f;
    float *X1F1, *Z2F2, *HW, *HeW, *X3, *Z4;
    int* dt;
    void* out;
};

__device__ __forceinline__ void adjA_slot(const PipeArgs& a, int k, const float* sn,
                                          float* aea, float* colmax) {
    int e = k >> 6, s = k & 63;
    if (s >= min(a.aec[e], CAP)) return;
    int f = a.aej[k];
    float M;
    if (e == f) {
        M = 1.f;
    } else {
        M = 0.f;
        int ce = min(a.tcnt[e], 2), cf = min(a.tcnt[f], 2);
        for (int x = 0; x < ce; x++) {
            int nx = a.trows[2 * e + x]; float ux = a.tvals[2 * e + x];
            for (int y = 0; y < cf; y++)
                if (a.trows[2 * f + y] == nx) M += ux * a.tvals[2 * f + y] * sn[nx];
        }
    }
    float v = M * a.aev[k];
    aea[k] = v;
    if (v > 0.f) atomicMax((int*)&colmax[f], __float_as_int(v));
}

extern "C" __global__ void __launch_bounds__(256)
k_pipeline(PipeArgs a) {
    cg::grid_group grid = cg::this_grid();
    int tid = blockIdx.x * 256 + threadIdx.x;
    int wv = tid >> 6, ln = tid & 63;

    // ---------- S0: avco init (x3) + edge_map ----------
    for (int idx = tid; idx < N_ * CAP; idx += BT) {
        int row = idx >> 6, s = idx & 63;
        float v = 0.f;
        if (s < min(a.avc[row], CAP) && a.avj[idx] == row) v = a.avv[idx];
        a.avco1[idx] = v; a.avco2[idx] = v; a.avco3[idx] = v;
    }
    if (tid < E_) {
        int e = tid;
        if (a.tcnt[e] < 2) {
            a.eav[2 * e] = -1; a.eav[2 * e + 1] = -1; a.eprod[e] = 0.f;
        } else {
            int p = a.trows[2 * e], q = a.trows[2 * e + 1];
            int ia = -1, ib = -1;
            int np = min(a.avc[p], CAP), nq = min(a.avc[q], CAP);
            for (int s = 0; s < np; s++) if (a.avj[p * CAP + s] == q) { ia = p * CAP + s; break; }
            for (int s = 0; s < nq; s++) if (a.avj[q * CAP + s] == p) { ib = q * CAP + s; break; }
            a.eav[2 * e] = ia; a.eav[2 * e + 1] = ib;
            a.eprod[e] = a.tvals[2 * e] * a.tvals[2 * e + 1];
        }
    }
    grid.sync();

    // ---------- S1: scatter1 | edge_feat | gemm W1 | gemmln Wf1 ----------
    if (tid < E_) {  // gate1 = Zf[e,:16].p1; scatter into avco1
        int e = tid;
        float ep = a.eprod[e];
        if (ep != 0.f) {
            const float4* zr = (const float4*)(a.Zf + (long long)e * 16);
            const float4* pr = (const float4*)a.p1f;
            float s = 0.f;
#pragma unroll
            for (int q = 0; q < 4; q++) {
                float4 h = zr[q], pp = pr[q];
                s += h.x * pp.x + h.y * pp.y + h.z * pp.z + h.w * pp.w;
            }
            float c = ep * s;
            int i1 = a.eav[2 * e], i2 = a.eav[2 * e + 1];
            if (i1 >= 0) unsafeAtomicAdd(&a.avco1[i1], a.avv[i1] * c);
            if (i2 >= 0) unsafeAtomicAdd(&a.avco1[i2], a.avv[i2] * c);
        }
    }
    if (tid >= E_ && tid < 2 * E_) {  // edge_feat: HeW = relu(Z)@W2; F2 = relu(LN(Z@Wf2))
        int e = tid - E_;
        const float4* zr = (const float4*)(a.Zf + (long long)e * 16);
        float zv[16];
        float4 z0 = zr[0], z1 = zr[1], z2 = zr[2], z3 = zr[3];
        zv[0] = z0.x; zv[1] = z0.y; zv[2] = z0.z; zv[3] = z0.w;
        zv[4] = z1.x; zv[5] = z1.y; zv[6] = z1.z; zv[7] = z1.w;
        zv[8] = z2.x; zv[9] = z2.y; zv[10] = z2.z; zv[11] = z2.w;
        zv[12] = z3.x; zv[13] = z3.y; zv[14] = z3.z; zv[15] = z3.w;
        float hw[16], f2[16];
#pragma unroll
        for (int c = 0; c < 16; c++) { hw[c] = 0.f; f2[c] = 0.f; }
#pragma unroll
        for (int k = 0; k < 16; k++) {
            float ar = fmaxf(zv[k], 0.f), az = zv[k];
#pragma unroll
            for (int c = 0; c < 16; c++) {
                hw[c] += ar * a.W2f[k * 16 + c];
                f2[c] += az * a.Wf2f[k * 16 + c];
            }
        }
        float m = 0.f;
#pragma unroll
        for (int c = 0; c < 16; c++) m += f2[c];
        m *= (1.f / 16.f);
        float var = 0.f;
#pragma unroll
        for (int c = 0; c < 16; c++) { float d = f2[c] - m; var += d * d; }
        var *= (1.f / 16.f);
        float rs = rsqrtf(var + 1e-5f);
#pragma unroll
        for (int c = 0; c < 16; c++)
            f2[c] = fmaxf((f2[c] - m) * rs * a.g2f[c] + a.be2f[c], 0.f);
        float4* ho = (float4*)(a.HeW + (long long)e * 16);
        ho[0] = make_float4(hw[0], hw[1], hw[2], hw[3]);
        ho[1] = make_float4(hw[4], hw[5], hw[6], hw[7]);
        ho[2] = make_float4(hw[8], hw[9], hw[10], hw[11]);
        ho[3] = make_float4(hw[12], hw[13], hw[14], hw[15]);
        float4* fo = (float4*)(a.Z2F2 + (long long)e * 32 + 16);
        fo[0] = make_float4(f2[0], f2[1], f2[2], f2[3]);
        fo[1] = make_float4(f2[4], f2[5], f2[6], f2[7]);
        fo[2] = make_float4(f2[8], f2[9], f2[10], f2[11]);
        fo[3] = make_float4(f2[12], f2[13], f2[14], f2[15]);
    }
    if (wv < 512) {  // gemm W1: HW = Xf @ W1 (K=64)
#pragma unroll
        for (int j = 0; j < 4; j++) {
            int r = wv + 512 * j;
            const float* xr = a.Xf + (long long)r * 64;
            float a0 = 0.f, a1 = 0.f;
            for (int k = 0; k < 64; k++) {
                float x = xr[k];
                a0 += x * a.W1f[k * 128 + ln];
                a1 += x * a.W1f[k * 128 + 64 + ln];
            }
            a.HW[(long long)r * 128 + ln] = a0;
            a.HW[(long long)r * 128 + 64 + ln] = a1;
        }
    } else {  // gemmln Wf1 -> F1 = relu(LN(X@Wf1)) into X1F1[:,128:]
#pragma unroll
        for (int j = 0; j < 4; j++) {
            int r = (wv - 512) + 512 * j;
            const float* xr = a.Xf + (long long)r * 64;
            float a0 = 0.f, a1 = 0.f;
            for (int k = 0; k < 64; k++) {
                float x = xr[k];
                a0 += x * a.Wf1f[k * 128 + ln];
                a1 += x * a.Wf1f[k * 128 + 64 + ln];
            }
            float m = wred64(a0 + a1) * (1.f / 128.f);
            float d0 = a0 - m, d1 = a1 - m;
            float var = wred64(d0 * d0 + d1 * d1) * (1.f / 128.f);
            float rs = rsqrtf(var + 1e-5f);
            a.X1F1[(long long)r * 256 + 128 + ln] =
                fmaxf(d0 * rs * a.g1f[ln] + a.be1f[ln], 0.f);
            a.X1F1[(long long)r * 256 + 192 + ln] =
                fmaxf(d1 * rs * a.g1f[64 + ln] + a.be1f[64 + ln], 0.f);
        }
    }
    grid.sync();

    // ---------- S2: apply_node1 -> X1; fused gate p2 -> s_n1 ----------
#pragma unroll
    for (int j = 0; j < 2; j++) {
        int i = wv + 1024 * j;
        float acc0 = a.b1f[ln], acc1 = a.b1f[64 + ln];
        int n = min(a.avc[i], CAP);
        for (int s = 0; s < n; s++) {
            int idx = i * CAP + s;
            float co = a.avco1[idx];
            const float* h = a.HW + (long long)a.avj[idx] * 128;
            acc0 += co * h[ln]; acc1 += co * h[64 + ln];
        }
        acc0 = fmaxf(acc0, 0.f); acc1 = fmaxf(acc1, 0.f);
        a.X1F1[(long long)i * 256 + ln] = acc0;
        a.X1F1[(long long)i * 256 + 64 + ln] = acc1;
        float f0 = a.X1F1[(long long)i * 256 + 128 + ln];
        float f1 = a.X1F1[(long long)i * 256 + 192 + ln];
        float contrib = acc0 * a.p2f[ln] + acc1 * a.p2f[64 + ln] +
                        f0 * a.p2f[128 + ln] + f1 * a.p2f[192 + ln];
        float sum = wred64(contrib);
        if (ln == 0) a.s_n1[i] = sum;
    }
    grid.sync();

    // ---------- S3: edge_adjA1 + gemm W3 (K=256) ----------
#pragma unroll
    for (int j = 0; j < 4; j++) adjA_slot(a, tid + j * BT, a.s_n1, a.aea1, a.colmax1);
#pragma unroll
    for (int j = 0; j < 2; j++) {
        int r = wv + 1024 * j;
        const float* xr = a.X1F1 + (long long)r * 256;
        float a0 = 0.f, a1 = 0.f;
        for (int k = 0; k < 256; k++) {
            float x = xr[k];
            a0 += x * a.W3f[k * 128 + ln];
            a1 += x * a.W3f[k * 128 + 64 + ln];
        }
        a.HW[(long long)r * 128 + ln] = a0;
        a.HW[(long long)r * 128 + 64 + ln] = a1;
    }
    grid.sync();

    // ---------- S4: apply_edge1 -> Z2; fused gate p3 + scatter avco2 ----------
    {
        int e = tid >> 4, c = tid & 15;
        float acc = a.b2f[c];
        int n = min(a.aec[e], CAP);
        for (int s = 0; s < n; s++) {
            int idx = e * CAP + s;
            int f = a.aej[idx];
            float cm = a.colmax1[f];
            float nv = (cm != 0.f) ? a.aea1[idx] / cm : 0.f;
            acc += nv * a.HeW[(long long)f * 16 + c];
        }
        acc = fmaxf(acc, 0.f);
        a.Z2F2[(long long)e * 32 + c] = acc;
        float f2 = a.Z2F2[(long long)e * 32 + 16 + c];
        float contrib = acc * a.p3f[c] + f2 * a.p3f[16 + c];
        float sum = wred16(contrib);
        if (c == 0) {
            float ep = a.eprod[e];
            if (ep != 0.f) {
                float cc = ep * sum;
                int i1 = a.eav[2 * e], i2 = a.eav[2 * e + 1];
                if (i1 >= 0) unsafeAtomicAdd(&a.avco2[i1], a.avv[i1] * cc);
                if (i2 >= 0) unsafeAtomicAdd(&a.avco2[i2], a.avv[i2] * cc);
            }
        }
    }
    grid.sync();

    // ---------- S5: apply_node3 -> X3; fused gate p4 -> s_n2 ----------
#pragma unroll
    for (int j = 0; j < 2; j++) {
        int i = wv + 1024 * j;
        float acc0 = a.b3f[ln], acc1 = a.b3f[64 + ln];
        int n = min(a.avc[i], CAP);
        for (int s = 0; s < n; s++) {
            int idx = i * CAP + s;
            float co = a.avco2[idx];
            const float* h = a.HW + (long long)a.avj[idx] * 128;
            acc0 += co * h[ln]; acc1 += co * h[64 + ln];
        }
        acc0 = fmaxf(acc0, 0.f); acc1 = fmaxf(acc1, 0.f);
        a.X3[(long long)i * 128 + ln] = acc0;
        a.X3[(long long)i * 128 + 64 + ln] = acc1;
        float contrib = acc0 * a.p4f[ln] + acc1 * a.p4f[64 + ln];
        float sum = wred64(contrib);
        if (ln == 0) a.s_n2[i] = sum;
    }
    grid.sync();

    // ---------- S6: edge_adjA2 + rowmat16 W4 + gemm W5 (K=128) ----------
#pragma unroll
    for (int j = 0; j < 4; j++) adjA_slot(a, tid + j * BT, a.s_n2, a.aea2, a.colmax2);
    if (tid < E_) {  // HeW = Z2F2 @ W4 [32x16]
        int e = tid;
        const float4* zr = (const float4*)(a.Z2F2 + (long long)e * 32);
        float zv[32];
#pragma unroll
        for (int q = 0; q < 8; q++) {
            float4 v = zr[q];
            zv[q * 4] = v.x; zv[q * 4 + 1] = v.y; zv[q * 4 + 2] = v.z; zv[q * 4 + 3] = v.w;
        }
        float o[16];
#pragma unroll
        for (int c = 0; c < 16; c++) o[c] = 0.f;
#pragma unroll
        for (int k = 0; k < 32; k++) {
            float av = zv[k];
#pragma unroll
            for (int c = 0; c < 16; c++) o[c] += av * a.W4f[k * 16 + c];
        }
        float4* oo = (float4*)(a.HeW + (long long)e * 16);
        oo[0] = make_float4(o[0], o[1], o[2], o[3]);
        oo[1] = make_float4(o[4], o[5], o[6], o[7]);
        oo[2] = make_float4(o[8], o[9], o[10], o[11]);
        oo[3] = make_float4(o[12], o[13], o[14], o[15]);
    }
#pragma unroll
    for (int j = 0; j < 2; j++) {
        int r = wv + 1024 * j;
        const float* xr = a.X3 + (long long)r * 128;
        float a0 = 0.f, a1 = 0.f;
        for (int k = 0; k < 128; k++) {
            float x = xr[k];
            a0 += x * a.W5f[k * 128 + ln];
            a1 += x * a.W5f[k * 128 + 64 + ln];
        }
        a.HW[(long long)r * 128 + ln] = a0;
        a.HW[(long long)r * 128 + 64 + ln] = a1;
    }
    grid.sync();

    // ---------- S7: apply_edge2 -> Z4; fused gate p5 + scatter avco3 ----------
    {
        int e = tid >> 4, c = tid & 15;
        float acc = a.b4f[c];
        int n = min(a.aec[e], CAP);
        for (int s = 0; s < n; s++) {
            int idx = e * CAP + s;
            int f = a.aej[idx];
            float cm = a.colmax2[f];
            float nv = (cm != 0.f) ? a.aea2[idx] / cm : 0.f;
            acc += nv * a.HeW[(long long)f * 16 + c];
        }
        acc = fmaxf(acc, 0.f);
        a.Z4[(long long)e * 16 + c] = acc;
        float contrib = acc * a.p5f[c];
        float sum = wred16(contrib);
        if (c == 0) {
            float ep = a.eprod[e];
            if (ep != 0.f) {
                float cc = ep * sum;
                int i1 = a.eav[2 * e], i2 = a.eav[2 * e + 1];
                if (i1 >= 0) unsafeAtomicAdd(&a.avco3[i1], a.avv[i1] * cc);
                if (i2 >= 0) unsafeAtomicAdd(&a.avco3[i2], a.avv[i2] * cc);
            }
        }
    }
    grid.sync();

    // ---------- S8: apply_node5 -> d_out ----------
    int isbf = a.dt[1];
#pragma unroll
    for (int j = 0; j < 2; j++) {
        int i = wv + 1024 * j;
        float acc0 = a.b5f[ln], acc1 = a.b5f[64 + ln];
        int n = min(a.avc[i], CAP);
        for (int s = 0; s < n; s++) {
            int idx = i * CAP + s;
            float co = a.avco3[idx];
            const float* h = a.HW + (long long)a.avj[idx] * 128;
            acc0 += co * h[ln]; acc1 += co * h[64 + ln];
        }
        if (isbf) {
            ((bf16*)a.out)[(long long)i * 128 + ln] = __float2bfloat16(acc0);
            ((bf16*)a.out)[(long long)i * 128 + 64 + ln] = __float2bfloat16(acc1);
        } else {
            ((float*)a.out)[(long long)i * 128 + ln] = acc0;
            ((float*)a.out)[(long long)i * 128 + 64 + ln] = acc1;
        }
    }
}

extern "C" void kernel_launch(void* const* d_in, const int* in_sizes, int n_in,
                              void* d_out, int out_size, void* d_ws, size_t ws_size,
                              hipStream_t stream) {
    char* wsB = (char*)d_ws;
    size_t off = 0;
    auto alloc = [&](size_t bytes) -> void* {
        void* p = wsB + off;
        off += (bytes + 255) & ~(size_t)255;
        return p;
    };
    // --- contiguous zero-init block (single memset) ---
    int*   dt      = (int*)alloc(2 * 4);
    int*   tcnt    = (int*)alloc(E_ * 4);
    int*   avc     = (int*)alloc(N_ * 4);
    int*   aec     = (int*)alloc(E_ * 4);
    float* colmax1 = (float*)alloc(E_ * 4);
    float* colmax2 = (float*)alloc(E_ * 4);
    size_t zero_bytes = off;
    // --- converted f32 inputs ---
    float* Xf  = (float*)alloc((size_t)N_ * 64 * 4);
    float* Zf  = (float*)alloc((size_t)E_ * 16 * 4);
    float* W1f = (float*)alloc(8192 * 4);  float* p1f = (float*)alloc(16 * 4);
    float* b1f = (float*)alloc(128 * 4);
    float* Wf1f = (float*)alloc(8192 * 4); float* g1f = (float*)alloc(128 * 4);
    float* be1f = (float*)alloc(128 * 4);
    float* W2f = (float*)alloc(256 * 4);   float* p2f = (float*)alloc(256 * 4);
    float* b2f = (float*)alloc(16 * 4);
    float* Wf2f = (float*)alloc(256 * 4);  float* g2f = (float*)alloc(16 * 4);
    float* be2f = (float*)alloc(16 * 4);
    float* W3f = (float*)alloc(32768 * 4); float* p3f = (float*)alloc(32 * 4);
    float* b3f = (float*)alloc(128 * 4);
    float* W4f = (float*)alloc(512 * 4);   float* p4f = (float*)alloc(128 * 4);
    float* b4f = (float*)alloc(16 * 4);
    float* W5f = (float*)alloc(16384 * 4); float* p5f = (float*)alloc(16 * 4);
    float* b5f = (float*)alloc(128 * 4);
    // --- sparse structures + activations ---
    int*   trows  = (int*)alloc(E_ * 2 * 4);
    float* tvals  = (float*)alloc(E_ * 2 * 4);
    int*   avj    = (int*)alloc((size_t)N_ * CAP * 4);
    float* avv    = (float*)alloc((size_t)N_ * CAP * 4);
    int*   aej    = (int*)alloc((size_t)E_ * CAP * 4);
    float* aev    = (float*)alloc((size_t)E_ * CAP * 4);
    float* aea1   = (float*)alloc((size_t)E_ * CAP * 4);
    float* aea2   = (float*)alloc((size_t)E_ * CAP * 4);
    int*   eav    = (int*)alloc(E_ * 2 * 4);
    float* eprod  = (float*)alloc(E_ * 4);
    float* s_n1   = (float*)alloc(N_ * 4);
    float* s_n2   = (float*)alloc(N_ * 4);
    float* avco1  = (float*)alloc((size_t)N_ * CAP * 4);
    float* avco2  = (float*)alloc((size_t)N_ * CAP * 4);
    float* avco3  = (float*)alloc((size_t)N_ * CAP * 4);
    float* X1F1   = (float*)alloc((size_t)N_ * 256 * 4);
    float* Z2F2   = (float*)alloc((size_t)E_ * 32 * 4);
    float* HW     = (float*)alloc((size_t)N_ * 128 * 4);
    float* HeW    = (float*)alloc((size_t)E_ * 16 * 4);
    float* X3     = (float*)alloc((size_t)N_ * 128 * 4);
    float* Z4     = (float*)alloc((size_t)E_ * 16 * 4);

    hipMemsetAsync(dt, 0, zero_bytes, stream);

    // 1) dtype detect (first 8.4 MB of T as u32; safe under either dtype)
    k_detect<<<2048, 256, 0, stream>>>((const unsigned int*)d_in[4], dt + 1);

    // 2) fused extraction + upconvert
    ConvArgs ca{};
    int ne = 0;
    auto addc = [&](const void* s, float* d, int n) {
        ca.src[ne] = s; ca.dst[ne] = d; ca.n[ne] = n; ne++;
    };
    addc(d_in[0], Xf, N_ * 64);  addc(d_in[1], Zf, E_ * 16);
    addc(d_in[5], W1f, 8192);   addc(d_in[6], p1f, 16);   addc(d_in[7], b1f, 128);
    addc(d_in[8], Wf1f, 8192);  addc(d_in[9], g1f, 128);  addc(d_in[10], be1f, 128);
    addc(d_in[11], W2f, 256);   addc(d_in[12], p2f, 256); addc(d_in[13], b2f, 16);
    addc(d_in[14], Wf2f, 256);  addc(d_in[15], g2f, 16);  addc(d_in[16], be2f, 16);
    addc(d_in[17], W3f, 32768); addc(d_in[18], p3f, 32);  addc(d_in[19], b3f, 128);
    addc(d_in[20], W4f, 512);   addc(d_in[21], p4f, 128); addc(d_in[22], b4f, 16);
    addc(d_in[23], W5f, 16384); addc(d_in[24], p5f, 16);  addc(d_in[25], b5f, 128);
    int nb = 0;
    for (int e = 0; e < ne; e++) {
        ca.first[e] = nb;
        int k = (ca.n[e] + CHUNK - 1) / CHUNK;
        for (int j = 0; j < k; j++) ca.blk_entry[nb++] = (unsigned char)e;
    }
    ExtractArgs ea{d_in[4], d_in[3], d_in[2], dt,
                   tcnt, trows, tvals, avc, avj, avv, aec, aej, aev};
    k_extract_all<<<14336 + nb, 256, 0, stream>>>(ea, ca);

    // 3) cooperative pipeline (everything else)
    PipeArgs pa{tcnt, trows, tvals, avc, avj, avv, aec, aej, aev,
                eav, eprod, avco1, avco2, avco3, aea1, aea2, colmax1, colmax2,
                s_n1, s_n2, Xf, Zf,
                W1f, p1f, b1f, Wf1f, g1f, be1f,
                W2f, p2f, b2f, Wf2f, g2f, be2f,
                W3f, p3f, b3f, W4f, p4f, b4f,
                W5f, p5f, b5f,
                X1F1, Z2F2, HW, HeW, X3, Z4, dt, d_out};
    void* args[] = {&pa};
    hipLaunchCooperativeKernel((void*)k_pipeline, dim3(256), dim3(256), args, 0, stream);
}

// Round 7
// 253.782 us; speedup vs baseline: 2.1933x; 2.1933x over previous
//
#include <hip/hip_runtime.h>
#include <hip/hip_bf16.h>

using bf16 = __hip_bfloat16;

constexpr int N_ = 2048;    // nodes
constexpr int E_ = 4096;    // edges
constexpr int CAP = 64;     // max nnz per adjacency row

__device__ __forceinline__ void unpack8(uint4 u, float* f) {
    unsigned w0 = u.x, w1 = u.y, w2 = u.z, w3 = u.w;
    f[0] = __uint_as_float(w0 << 16); f[1] = __uint_as_float(w0 & 0xffff0000u);
    f[2] = __uint_as_float(w1 << 16); f[3] = __uint_as_float(w1 & 0xffff0000u);
    f[4] = __uint_as_float(w2 << 16); f[5] = __uint_as_float(w2 & 0xffff0000u);
    f[6] = __uint_as_float(w3 << 16); f[7] = __uint_as_float(w3 & 0xffff0000u);
}

__device__ __forceinline__ void load8(const void* p, long long base, int isbf, float* f) {
    if (isbf) {
        uint4 u = *(const uint4*)((const unsigned short*)p + base);
        unpack8(u, f);
    } else {
        const float4* q = (const float4*)((const float*)p + base);
        float4 a = q[0], b = q[1];
        f[0] = a.x; f[1] = a.y; f[2] = a.z; f[3] = a.w;
        f[4] = b.x; f[5] = b.y; f[6] = b.z; f[7] = b.w;
    }
}

// ---- dtype detect: T holds {0,1,2}; f32 stream -> low16 of every u32 is 0
__global__ void k_detect(const unsigned int* __restrict__ t32, int* __restrict__ flag) {
    long long i = (long long)(blockIdx.x * blockDim.x + threadIdx.x) * 4;
    uint4 u = *(const uint4*)(t32 + i);
    if ((u.x | u.y | u.z | u.w) & 0xFFFFu) *flag = 1;
}

// ---- fused extraction + upconvert (one dispatch, block-partitioned)
constexpr int NCONV = 23;
constexpr int CHUNK = 8192;
struct ConvArgs {
    const void* src[NCONV];
    float* dst[NCONV];
    int n[NCONV];
    int first[NCONV];
    unsigned char blk_entry[64];
};

struct GArgs {
    const void* T; const void* adjV; const void* adjE;
    int* dt;
    int* tcnt; int* trows; float* tvals;
    int* avc; int* avj; float* avv;
    int* aec; int* aej; float* aev;
    int* eav; float* eprod;
    float *d1, *d2, *d3;            // avco deltas (zeroed by memset)
    float *aea1, *aea2, *colmax1, *colmax2;
    float *s_n1, *s_n2;
    float *Xf, *Zf;
    float *W1f, *p1f, *b1f, *Wf1f, *g1f, *be1f;
    float *W2f, *p2f, *b2f, *Wf2f, *g2f, *be2f;
    float *W3f, *p3f, *b3f, *W4f, *p4f, *b4f;
    float *W5f, *p5f, *b5f;
    float *X1F1, *Z2F2, *HW, *HeW, *X3, *Z4;
    void* out;
};

__global__ void k_extract_all(GArgs a, ConvArgs ca) {
    int b = blockIdx.x, t = threadIdx.x;
    int isbf = a.dt[1];
    if (b < 4096) {                 // T: N*E
        long long base = ((long long)b * 256 + t) * 8;
        float f[8]; load8(a.T, base, isbf, f);
#pragma unroll
        for (int k = 0; k < 8; k++) {
            if (f[k] != 0.f) {
                long long idx = base + k;
                int e = (int)(idx & (E_ - 1));
                int n = (int)(idx >> 12);
                int p = atomicAdd(&a.tcnt[e], 1);
                if (p < 2) { a.trows[e * 2 + p] = n; a.tvals[e * 2 + p] = f[k]; }
            }
        }
    } else if (b < 6144) {          // adjV: N*N
        long long base = ((long long)(b - 4096) * 256 + t) * 8;
        float f[8]; load8(a.adjV, base, isbf, f);
#pragma unroll
        for (int k = 0; k < 8; k++) {
            if (f[k] != 0.f) {
                long long idx = base + k;
                int row = (int)(idx >> 11), col = (int)(idx & (N_ - 1));
                int s = atomicAdd(&a.avc[row], 1);
                if (s < CAP) { a.avj[row * CAP + s] = col; a.avv[row * CAP + s] = f[k]; }
            }
        }
    } else if (b < 14336) {         // adjE: E*E
        long long base = ((long long)(b - 6144) * 256 + t) * 8;
        float f[8]; load8(a.adjE, base, isbf, f);
#pragma unroll
        for (int k = 0; k < 8; k++) {
            if (f[k] != 0.f) {
                long long idx = base + k;
                int row = (int)(idx >> 12), col = (int)(idx & (E_ - 1));
                int s = atomicAdd(&a.aec[row], 1);
                if (s < CAP) { a.aej[row * CAP + s] = col; a.aev[row * CAP + s] = f[k]; }
            }
        }
    } else {                        // upconvert inputs to f32
        int gb = b - 14336;
        int e = ca.blk_entry[gb];
        int off = (gb - ca.first[e]) * CHUNK;
        int n = ca.n[e];
        const void* src = ca.src[e];
        float* dst = ca.dst[e];
        int lim = min(off + CHUNK, n);
        for (int i = off + t * 8; i < lim; i += 256 * 8) {
            float f[8]; load8(src, i, isbf, f);
            float4* d = (float4*)(dst + i);
            d[0] = make_float4(f[0], f[1], f[2], f[3]);
            d[1] = make_float4(f[4], f[5], f[6], f[7]);
        }
    }
}

// ---- stage A (after extract): edge_map+gate1+scatter1 | edge_feat | gemm W1 | gemmln Wf1
__global__ void __launch_bounds__(128) k_stageA(GArgs a) {
    __shared__ float arow[256];
    __shared__ float sm[2];
    int b = blockIdx.x, t = threadIdx.x;
    if (b < 32) {                   // per-edge: map + gate p1 + scatter into d1
        int e = b * 128 + t;
        if (a.tcnt[e] < 2) { a.eav[2 * e] = -1; a.eav[2 * e + 1] = -1; a.eprod[e] = 0.f; return; }
        int p = a.trows[2 * e], q = a.trows[2 * e + 1];
        int ia = -1, ib = -1;
        int np = min(a.avc[p], CAP), nq = min(a.avc[q], CAP);
        for (int s = 0; s < np; s++) if (a.avj[p * CAP + s] == q) { ia = p * CAP + s; break; }
        for (int s = 0; s < nq; s++) if (a.avj[q * CAP + s] == p) { ib = q * CAP + s; break; }
        float ep = a.tvals[2 * e] * a.tvals[2 * e + 1];
        a.eav[2 * e] = ia; a.eav[2 * e + 1] = ib; a.eprod[e] = ep;
        const float4* zr = (const float4*)(a.Zf + (long long)e * 16);
        const float4* pr = (const float4*)a.p1f;
        float s = 0.f;
#pragma unroll
        for (int qq = 0; qq < 4; qq++) {
            float4 h = zr[qq], pp = pr[qq];
            s += h.x * pp.x + h.y * pp.y + h.z * pp.z + h.w * pp.w;
        }
        float c = ep * s;
        if (ia >= 0) unsafeAtomicAdd(&a.d1[ia], a.avv[ia] * c);
        if (ib >= 0) unsafeAtomicAdd(&a.d1[ib], a.avv[ib] * c);
    } else if (b < 64) {            // edge_feat: HeW = relu(Z)@W2 ; F2 = relu(LN(Z@Wf2))
        int e = (b - 32) * 128 + t;
        const float4* zr = (const float4*)(a.Zf + (long long)e * 16);
        float zv[16];
        float4 z0 = zr[0], z1 = zr[1], z2 = zr[2], z3 = zr[3];
        zv[0] = z0.x; zv[1] = z0.y; zv[2] = z0.z; zv[3] = z0.w;
        zv[4] = z1.x; zv[5] = z1.y; zv[6] = z1.z; zv[7] = z1.w;
        zv[8] = z2.x; zv[9] = z2.y; zv[10] = z2.z; zv[11] = z2.w;
        zv[12] = z3.x; zv[13] = z3.y; zv[14] = z3.z; zv[15] = z3.w;
        float hw[16], f2[16];
#pragma unroll
        for (int c = 0; c < 16; c++) { hw[c] = 0.f; f2[c] = 0.f; }
#pragma unroll
        for (int k = 0; k < 16; k++) {
            float ar = fmaxf(zv[k], 0.f), az = zv[k];
#pragma unroll
            for (int c = 0; c < 16; c++) {
                hw[c] += ar * a.W2f[k * 16 + c];
                f2[c] += az * a.Wf2f[k * 16 + c];
            }
        }
        float m = 0.f;
#pragma unroll
        for (int c = 0; c < 16; c++) m += f2[c];
        m *= (1.f / 16.f);
        float var = 0.f;
#pragma unroll
        for (int c = 0; c < 16; c++) { float d = f2[c] - m; var += d * d; }
        var *= (1.f / 16.f);
        float rs = rsqrtf(var + 1e-5f);
#pragma unroll
        for (int c = 0; c < 16; c++)
            f2[c] = fmaxf((f2[c] - m) * rs * a.g2f[c] + a.be2f[c], 0.f);
        float4* ho = (float4*)(a.HeW + (long long)e * 16);
        ho[0] = make_float4(hw[0], hw[1], hw[2], hw[3]);
        ho[1] = make_float4(hw[4], hw[5], hw[6], hw[7]);
        ho[2] = make_float4(hw[8], hw[9], hw[10], hw[11]);
        ho[3] = make_float4(hw[12], hw[13], hw[14], hw[15]);
        float4* fo = (float4*)(a.Z2F2 + (long long)e * 32 + 16);
        fo[0] = make_float4(f2[0], f2[1], f2[2], f2[3]);
        fo[1] = make_float4(f2[4], f2[5], f2[6], f2[7]);
        fo[2] = make_float4(f2[8], f2[9], f2[10], f2[11]);
        fo[3] = make_float4(f2[12], f2[13], f2[14], f2[15]);
    } else if (b < 2112) {          // gemm W1: HW = Xf @ W1 (K=64)
        int i = b - 64;
        if (t < 64) arow[t] = a.Xf[(long long)i * 64 + t];
        __syncthreads();
        float acc = 0.f;
        for (int k = 0; k < 64; k++) acc += arow[k] * a.W1f[k * 128 + t];
        a.HW[(long long)i * 128 + t] = acc;
    } else {                        // gemmln Wf1 -> F1 into X1F1[:,128:]
        int i = b - 2112;
        if (t < 64) arow[t] = a.Xf[(long long)i * 64 + t];
        __syncthreads();
        float acc = 0.f;
        for (int k = 0; k < 64; k++) acc += arow[k] * a.Wf1f[k * 128 + t];
        float v = acc;
        for (int o = 32; o > 0; o >>= 1) v += __shfl_down(v, o);
        if ((t & 63) == 0) sm[t >> 6] = v;
        __syncthreads();
        float mean = (sm[0] + sm[1]) * (1.f / 128.f);
        __syncthreads();
        float d = acc - mean;
        v = d * d;
        for (int o = 32; o > 0; o >>= 1) v += __shfl_down(v, o);
        if ((t & 63) == 0) sm[t >> 6] = v;
        __syncthreads();
        float var = (sm[0] + sm[1]) * (1.f / 128.f);
        float y = d * rsqrtf(var + 1e-5f) * a.g1f[t] + a.be1f[t];
        a.X1F1[(long long)i * 256 + 128 + t] = fmaxf(y, 0.f);
    }
}

// ---- apply_node (delta form) + fused gate p2 -> s_n1
__global__ void __launch_bounds__(128) k_node1(GArgs a) {
    __shared__ float sm[2];
    int i = blockIdx.x, c = threadIdx.x;
    float acc = a.b1f[c];
    int n = min(a.avc[i], CAP);
    for (int s = 0; s < n; s++) {
        int idx = i * CAP + s;
        int col = a.avj[idx];
        float co = (col == i) ? a.avv[idx] : a.d1[idx];
        acc += co * a.HW[(long long)col * 128 + c];
    }
    acc = fmaxf(acc, 0.f);
    a.X1F1[(long long)i * 256 + c] = acc;
    float f = a.X1F1[(long long)i * 256 + 128 + c];
    float v = acc * a.p2f[c] + f * a.p2f[128 + c];
    for (int o = 32; o > 0; o >>= 1) v += __shfl_down(v, o);
    if ((c & 63) == 0) sm[c >> 6] = v;
    __syncthreads();
    if (c == 0) a.s_n1[i] = sm[0] + sm[1];
}

__device__ __forceinline__ void adjA_slot(const GArgs& a, int k, const float* sn,
                                          float* aea, float* colmax) {
    int e = k >> 6, s = k & 63;
    if (s >= min(a.aec[e], CAP)) return;
    int f = a.aej[k];
    float M;
    if (e == f) {
        M = 1.f;
    } else {
        M = 0.f;
        int ce = min(a.tcnt[e], 2), cf = min(a.tcnt[f], 2);
        for (int x = 0; x < ce; x++) {
            int nx = a.trows[2 * e + x]; float ux = a.tvals[2 * e + x];
            for (int y = 0; y < cf; y++)
                if (a.trows[2 * f + y] == nx) M += ux * a.tvals[2 * f + y] * sn[nx];
        }
    }
    float v = M * a.aev[k];
    aea[k] = v;
    if (v > 0.f) atomicMax((int*)&colmax[f], __float_as_int(v));
}

// ---- stage C: adjA1 | gemm W3 (K=256)
__global__ void __launch_bounds__(128) k_stageC(GArgs a) {
    __shared__ float arow[256];
    int b = blockIdx.x, t = threadIdx.x;
    if (b < 2048) {
        adjA_slot(a, b * 128 + t, a.s_n1, a.aea1, a.colmax1);
    } else {
        int i = b - 2048;
        arow[t] = a.X1F1[(long long)i * 256 + t];
        arow[t + 128] = a.X1F1[(long long)i * 256 + 128 + t];
        __syncthreads();
        float acc = 0.f;
        for (int k = 0; k < 256; k++) acc += arow[k] * a.W3f[k * 128 + t];
        a.HW[(long long)i * 128 + t] = acc;
    }
}

// ---- apply_edge1 + fused gate p3 + scatter into d2
__global__ void __launch_bounds__(128) k_edge1(GArgs a) {
    int gt = blockIdx.x * 128 + threadIdx.x;
    int e = gt >> 4, c = gt & 15;
    float acc = a.b2f[c];
    int n = min(a.aec[e], CAP);
    for (int s = 0; s < n; s++) {
        int idx = e * CAP + s;
        int f = a.aej[idx];
        float cm = a.colmax1[f];
        float nv = (cm != 0.f) ? a.aea1[idx] / cm : 0.f;
        acc += nv * a.HeW[(long long)f * 16 + c];
    }
    acc = fmaxf(acc, 0.f);
    a.Z2F2[(long long)e * 32 + c] = acc;
    float f2 = a.Z2F2[(long long)e * 32 + 16 + c];
    float v = acc * a.p3f[c] + f2 * a.p3f[16 + c];
#pragma unroll
    for (int m = 1; m < 16; m <<= 1) v += __shfl_xor(v, m);
    if (c == 0) {
        float ep = a.eprod[e];
        if (ep != 0.f) {
            float cc = ep * v;
            int i1 = a.eav[2 * e], i2 = a.eav[2 * e + 1];
            if (i1 >= 0) unsafeAtomicAdd(&a.d2[i1], a.avv[i1] * cc);
            if (i2 >= 0) unsafeAtomicAdd(&a.d2[i2], a.avv[i2] * cc);
        }
    }
}

// ---- apply_node3 + fused gate p4 -> s_n2
__global__ void __launch_bounds__(128) k_node3(GArgs a) {
    __shared__ float sm[2];
    int i = blockIdx.x, c = threadIdx.x;
    float acc = a.b3f[c];
    int n = min(a.avc[i], CAP);
    for (int s = 0; s < n; s++) {
        int idx = i * CAP + s;
        int col = a.avj[idx];
        float co = (col == i) ? a.avv[idx] : a.d2[idx];
        acc += co * a.HW[(long long)col * 128 + c];
    }
    acc = fmaxf(acc, 0.f);
    a.X3[(long long)i * 128 + c] = acc;
    float v = acc * a.p4f[c];
    for (int o = 32; o > 0; o >>= 1) v += __shfl_down(v, o);
    if ((c & 63) == 0) sm[c >> 6] = v;
    __syncthreads();
    if (c == 0) a.s_n2[i] = sm[0] + sm[1];
}

// ---- stage F: adjA2 | rowmat W4 | gemm W5 (K=128)
__global__ void __launch_bounds__(128) k_stageF(GArgs a) {
    __shared__ float arow[128];
    int b = blockIdx.x, t = threadIdx.x;
    if (b < 2048) {
        adjA_slot(a, b * 128 + t, a.s_n2, a.aea2, a.colmax2);
    } else if (b < 2080) {          // HeW = Z2F2 @ W4 [32x16]
        int e = (b - 2048) * 128 + t;
        const float4* zr = (const float4*)(a.Z2F2 + (long long)e * 32);
        float zv[32];
#pragma unroll
        for (int q = 0; q < 8; q++) {
            float4 v = zr[q];
            zv[q * 4] = v.x; zv[q * 4 + 1] = v.y; zv[q * 4 + 2] = v.z; zv[q * 4 + 3] = v.w;
        }
        float o[16];
#pragma unroll
        for (int c = 0; c < 16; c++) o[c] = 0.f;
#pragma unroll
        for (int k = 0; k < 32; k++) {
            float av = zv[k];
#pragma unroll
            for (int c = 0; c < 16; c++) o[c] += av * a.W4f[k * 16 + c];
        }
        float4* oo = (float4*)(a.HeW + (long long)e * 16);
        oo[0] = make_float4(o[0], o[1], o[2], o[3]);
        oo[1] = make_float4(o[4], o[5], o[6], o[7]);
        oo[2] = make_float4(o[8], o[9], o[10], o[11]);
        oo[3] = make_float4(o[12], o[13], o[14], o[15]);
    } else {                        // gemm W5
        int i = b - 2080;
        arow[t] = a.X3[(long long)i * 128 + t];
        __syncthreads();
        float acc = 0.f;
        for (int k = 0; k < 128; k++) acc += arow[k] * a.W5f[k * 128 + t];
        a.HW[(long long)i * 128 + t] = acc;
    }
}

// ---- apply_edge2 + fused gate p5 + scatter into d3
__global__ void __launch_bounds__(128) k_edge2(GArgs a) {
    int gt = blockIdx.x * 128 + threadIdx.x;
    int e = gt >> 4, c = gt & 15;
    float acc = a.b4f[c];
    int n = min(a.aec[e], CAP);
    for (int s = 0; s < n; s++) {
        int idx = e * CAP + s;
        int f = a.aej[idx];
        float cm = a.colmax2[f];
        float nv = (cm != 0.f) ? a.aea2[idx] / cm : 0.f;
        acc += nv * a.HeW[(long long)f * 16 + c];
    }
    acc = fmaxf(acc, 0.f);
    a.Z4[(long long)e * 16 + c] = acc;
    float v = acc * a.p5f[c];
#pragma unroll
    for (int m = 1; m < 16; m <<= 1) v += __shfl_xor(v, m);
    if (c == 0) {
        float ep = a.eprod[e];
        if (ep != 0.f) {
            float cc = ep * v;
            int i1 = a.eav[2 * e], i2 = a.eav[2 * e + 1];
            if (i1 >= 0) unsafeAtomicAdd(&a.d3[i1], a.avv[i1] * cc);
            if (i2 >= 0) unsafeAtomicAdd(&a.d3[i2], a.avv[i2] * cc);
        }
    }
}

// ---- apply_node5 -> d_out (dtype follows dt[1])
__global__ void __launch_bounds__(128) k_node5(GArgs a) {
    int i = blockIdx.x, c = threadIdx.x;
    float acc = a.b5f[c];
    int n = min(a.avc[i], CAP);
    for (int s = 0; s < n; s++) {
        int idx = i * CAP + s;
        int col = a.avj[idx];
        float co = (col == i) ? a.avv[idx] : a.d3[idx];
        acc += co * a.HW[(long long)col * 128 + c];
    }
    if (a.dt[1]) ((bf16*)a.out)[(long long)i * 128 + c] = __float2bfloat16(acc);
    else         ((float*)a.out)[(long long)i * 128 + c] = acc;
}

extern "C" void kernel_launch(void* const* d_in, const int* in_sizes, int n_in,
                              void* d_out, int out_size, void* d_ws, size_t ws_size,
                              hipStream_t stream) {
    char* wsB = (char*)d_ws;
    size_t off = 0;
    auto alloc = [&](size_t bytes) -> void* {
        void* p = wsB + off;
        off += (bytes + 255) & ~(size_t)255;
        return p;
    };
    // --- contiguous zero-init block (single memset ~1.65 MB) ---
    int*   dt      = (int*)alloc(2 * 4);
    int*   tcnt    = (int*)alloc(E_ * 4);
    int*   avc     = (int*)alloc(N_ * 4);
    int*   aec     = (int*)alloc(E_ * 4);
    float* colmax1 = (float*)alloc(E_ * 4);
    float* colmax2 = (float*)alloc(E_ * 4);
    float* d1      = (float*)alloc((size_t)N_ * CAP * 4);
    float* d2      = (float*)alloc((size_t)N_ * CAP * 4);
    float* d3      = (float*)alloc((size_t)N_ * CAP * 4);
    size_t zero_bytes = off;
    // --- converted f32 inputs ---
    float* Xf  = (float*)alloc((size_t)N_ * 64 * 4);
    float* Zf  = (float*)alloc((size_t)E_ * 16 * 4);
    float* W1f = (float*)alloc(8192 * 4);  float* p1f = (float*)alloc(16 * 4);
    float* b1f = (float*)alloc(128 * 4);
    float* Wf1f = (float*)alloc(8192 * 4); float* g1f = (float*)alloc(128 * 4);
    float* be1f = (float*)alloc(128 * 4);
    float* W2f = (float*)alloc(256 * 4);   float* p2f = (float*)alloc(256 * 4);
    float* b2f = (float*)alloc(16 * 4);
    float* Wf2f = (float*)alloc(256 * 4);  float* g2f = (float*)alloc(16 * 4);
    float* be2f = (float*)alloc(16 * 4);
    float* W3f = (float*)alloc(32768 * 4); float* p3f = (float*)alloc(32 * 4);
    float* b3f = (float*)alloc(128 * 4);
    float* W4f = (float*)alloc(512 * 4);   float* p4f = (float*)alloc(128 * 4);
    float* b4f = (float*)alloc(16 * 4);
    float* W5f = (float*)alloc(16384 * 4); float* p5f = (float*)alloc(16 * 4);
    float* b5f = (float*)alloc(128 * 4);
    // --- sparse structures + activations ---
    int*   trows  = (int*)alloc(E_ * 2 * 4);
    float* tvals  = (float*)alloc(E_ * 2 * 4);
    int*   avj    = (int*)alloc((size_t)N_ * CAP * 4);
    float* avv    = (float*)alloc((size_t)N_ * CAP * 4);
    int*   aej    = (int*)alloc((size_t)E_ * CAP * 4);
    float* aev    = (float*)alloc((size_t)E_ * CAP * 4);
    float* aea1   = (float*)alloc((size_t)E_ * CAP * 4);
    float* aea2   = (float*)alloc((size_t)E_ * CAP * 4);
    int*   eav    = (int*)alloc(E_ * 2 * 4);
    float* eprod  = (float*)alloc(E_ * 4);
    float* s_n1   = (float*)alloc(N_ * 4);
    float* s_n2   = (float*)alloc(N_ * 4);
    float* X1F1   = (float*)alloc((size_t)N_ * 256 * 4);
    float* Z2F2   = (float*)alloc((size_t)E_ * 32 * 4);
    float* HW     = (float*)alloc((size_t)N_ * 128 * 4);
    float* HeW    = (float*)alloc((size_t)E_ * 16 * 4);
    float* X3     = (float*)alloc((size_t)N_ * 128 * 4);
    float* Z4     = (float*)alloc((size_t)E_ * 16 * 4);

    hipMemsetAsync(dt, 0, zero_bytes, stream);

    // 1) dtype detect
    k_detect<<<2048, 256, 0, stream>>>((const unsigned int*)d_in[4], dt + 1);

    // 2) fused extraction + upconvert
    ConvArgs ca{};
    int ne = 0;
    auto addc = [&](const void* s, float* d, int n) {
        ca.src[ne] = s; ca.dst[ne] = d; ca.n[ne] = n; ne++;
    };
    addc(d_in[0], Xf, N_ * 64);  addc(d_in[1], Zf, E_ * 16);
    addc(d_in[5], W1f, 8192);   addc(d_in[6], p1f, 16);   addc(d_in[7], b1f, 128);
    addc(d_in[8], Wf1f, 8192);  addc(d_in[9], g1f, 128);  addc(d_in[10], be1f, 128);
    addc(d_in[11], W2f, 256);   addc(d_in[12], p2f, 256); addc(d_in[13], b2f, 16);
    addc(d_in[14], Wf2f, 256);  addc(d_in[15], g2f, 16);  addc(d_in[16], be2f, 16);
    addc(d_in[17], W3f, 32768); addc(d_in[18], p3f, 32);  addc(d_in[19], b3f, 128);
    addc(d_in[20], W4f, 512);   addc(d_in[21], p4f, 128); addc(d_in[22], b4f, 16);
    addc(d_in[23], W5f, 16384); addc(d_in[24], p5f, 16);  addc(d_in[25], b5f, 128);
    int nb = 0;
    for (int e = 0; e < ne; e++) {
        ca.first[e] = nb;
        int k = (ca.n[e] + CHUNK - 1) / CHUNK;
        for (int j = 0; j < k; j++) ca.blk_entry[nb++] = (unsigned char)e;
    }

    GArgs a{d_in[4], d_in[3], d_in[2], dt,
            tcnt, trows, tvals, avc, avj, avv, aec, aej, aev,
            eav, eprod, d1, d2, d3, aea1, aea2, colmax1, colmax2,
            s_n1, s_n2, Xf, Zf,
            W1f, p1f, b1f, Wf1f, g1f, be1f,
            W2f, p2f, b2f, Wf2f, g2f, be2f,
            W3f, p3f, b3f, W4f, p4f, b4f,
            W5f, p5f, b5f,
            X1F1, Z2F2, HW, HeW, X3, Z4, d_out};

    k_extract_all<<<14336 + nb, 256, 0, stream>>>(a, ca);

    // 3) pipeline: 8 stream-ordered batched dispatches
    k_stageA<<<4160, 128, 0, stream>>>(a);
    k_node1<<<N_, 128, 0, stream>>>(a);
    k_stageC<<<4096, 128, 0, stream>>>(a);
    k_edge1<<<E_ * 16 / 128, 128, 0, stream>>>(a);
    k_node3<<<N_, 128, 0, stream>>>(a);
    k_stageF<<<4128, 128, 0, stream>>>(a);
    k_edge2<<<E_ * 16 / 128, 128, 0, stream>>>(a);
    k_node5<<<N_, 128, 0, stream>>>(a);
}

// Round 8
// 249.559 us; speedup vs baseline: 2.2304x; 1.0169x over previous
//
#include <hip/hip_runtime.h>
#include <hip/hip_bf16.h>

using bf16 = __hip_bfloat16;

constexpr int N_ = 2048;    // nodes
constexpr int E_ = 4096;    // edges
constexpr int CAP = 64;     // max nnz per adjacency row

__device__ __forceinline__ void unpack8(uint4 u, float* f) {
    unsigned w0 = u.x, w1 = u.y, w2 = u.z, w3 = u.w;
    f[0] = __uint_as_float(w0 << 16); f[1] = __uint_as_float(w0 & 0xffff0000u);
    f[2] = __uint_as_float(w1 << 16); f[3] = __uint_as_float(w1 & 0xffff0000u);
    f[4] = __uint_as_float(w2 << 16); f[5] = __uint_as_float(w2 & 0xffff0000u);
    f[6] = __uint_as_float(w3 << 16); f[7] = __uint_as_float(w3 & 0xffff0000u);
}

__device__ __forceinline__ void load8(const void* p, long long base, int isbf, float* f) {
    if (isbf) {
        uint4 u = *(const uint4*)((const unsigned short*)p + base);
        unpack8(u, f);
    } else {
        const float4* q = (const float4*)((const float*)p + base);
        float4 a = q[0], b = q[1];
        f[0] = a.x; f[1] = a.y; f[2] = a.z; f[3] = a.w;
        f[4] = b.x; f[5] = b.y; f[6] = b.z; f[7] = b.w;
    }
}

// ---- dtype detect: T holds {0,1,2}; f32 stream -> low16 of every u32 is 0
__global__ void k_detect(const unsigned int* __restrict__ t32, int* __restrict__ flag) {
    long long i = (long long)(blockIdx.x * blockDim.x + threadIdx.x) * 4;
    uint4 u = *(const uint4*)(t32 + i);
    if ((u.x | u.y | u.z | u.w) & 0xFFFFu) *flag = 1;
}

constexpr int NCONV = 23;
constexpr int CHUNK = 8192;
struct ConvArgs {
    const void* src[NCONV];
    float* dst[NCONV];
    int n[NCONV];
    int first[NCONV];
    unsigned char blk_entry[64];
};

struct GArgs {
    const void* T; const void* adjV; const void* adjE;
    int* dt;
    int* tcnt; int* trows; float* tvals;
    int* avc; int* avj; float* avv;
    int* aec; int* aej; float* aev;
    int* eav; float* eprod;
    float *d1, *d2, *d3;            // avco deltas (zeroed by memset)
    float *aea1, *aea2, *colmax1, *colmax2;
    float *s_n1, *s_n2;
    float *Xf, *Zf;
    float *W1f, *p1f, *b1f, *Wf1f, *g1f, *be1f;
    float *W2f, *p2f, *b2f, *Wf2f, *g2f, *be2f;
    float *W3f, *p3f, *b3f, *W4f, *p4f, *b4f;
    float *W5f, *p5f, *b5f;
    float *X1F1, *F2, *HW, *HeW, *HeW2, *X3;
    void* out;
};

// ---- fused extraction + upconvert; 16 elems/thread
__global__ void k_extract_all(GArgs a, ConvArgs ca) {
    int b = blockIdx.x, t = threadIdx.x;
    int isbf = a.dt[1];
    if (b < 2048) {                 // T: N*E = 8.4M
        long long base = ((long long)b * 256 + t) * 16;
        float f[16];
        load8(a.T, base, isbf, f); load8(a.T, base + 8, isbf, f + 8);
#pragma unroll
        for (int k = 0; k < 16; k++) {
            if (f[k] != 0.f) {
                long long idx = base + k;
                int e = (int)(idx & (E_ - 1));
                int n = (int)(idx >> 12);
                int p = atomicAdd(&a.tcnt[e], 1);
                if (p < 2) { a.trows[e * 2 + p] = n; a.tvals[e * 2 + p] = f[k]; }
            }
        }
    } else if (b < 3072) {          // adjV: N*N = 4.2M
        long long base = ((long long)(b - 2048) * 256 + t) * 16;
        float f[16];
        load8(a.adjV, base, isbf, f); load8(a.adjV, base + 8, isbf, f + 8);
#pragma unroll
        for (int k = 0; k < 16; k++) {
            if (f[k] != 0.f) {
                long long idx = base + k;
                int row = (int)(idx >> 11), col = (int)(idx & (N_ - 1));
                int s = atomicAdd(&a.avc[row], 1);
                if (s < CAP) { a.avj[row * CAP + s] = col; a.avv[row * CAP + s] = f[k]; }
            }
        }
    } else if (b < 7168) {          // adjE: E*E = 16.8M
        long long base = ((long long)(b - 3072) * 256 + t) * 16;
        float f[16];
        load8(a.adjE, base, isbf, f); load8(a.adjE, base + 8, isbf, f + 8);
#pragma unroll
        for (int k = 0; k < 16; k++) {
            if (f[k] != 0.f) {
                long long idx = base + k;
                int row = (int)(idx >> 12), col = (int)(idx & (E_ - 1));
                int s = atomicAdd(&a.aec[row], 1);
                if (s < CAP) { a.aej[row * CAP + s] = col; a.aev[row * CAP + s] = f[k]; }
            }
        }
    } else {                        // upconvert inputs to f32
        int gb = b - 7168;
        int e = ca.blk_entry[gb];
        int off = (gb - ca.first[e]) * CHUNK;
        int n = ca.n[e];
        const void* src = ca.src[e];
        float* dst = ca.dst[e];
        int lim = min(off + CHUNK, n);
        for (int i = off + t * 8; i < lim; i += 256 * 8) {
            float f[8]; load8(src, i, isbf, f);
            float4* d = (float4*)(dst + i);
            d[0] = make_float4(f[0], f[1], f[2], f[3]);
            d[1] = make_float4(f[4], f[5], f[6], f[7]);
        }
    }
}

// ---- stage A: edge_map+gate1+scatter1 | edge_feat | gemm W1 | gemmln Wf1
__global__ void __launch_bounds__(128) k_stageA(GArgs a) {
    __shared__ float arow[256];
    __shared__ float sm[2];
    int b = blockIdx.x, t = threadIdx.x;
    if (b < 32) {                   // per-edge: map + gate p1 + scatter into d1
        int e = b * 128 + t;
        if (a.tcnt[e] < 2) { a.eav[2 * e] = -1; a.eav[2 * e + 1] = -1; a.eprod[e] = 0.f; return; }
        int p = a.trows[2 * e], q = a.trows[2 * e + 1];
        int ia = -1, ib = -1;
        int np = min(a.avc[p], CAP), nq = min(a.avc[q], CAP);
        for (int s = 0; s < np; s++) if (a.avj[p * CAP + s] == q) { ia = p * CAP + s; break; }
        for (int s = 0; s < nq; s++) if (a.avj[q * CAP + s] == p) { ib = q * CAP + s; break; }
        float ep = a.tvals[2 * e] * a.tvals[2 * e + 1];
        a.eav[2 * e] = ia; a.eav[2 * e + 1] = ib; a.eprod[e] = ep;
        const float4* zr = (const float4*)(a.Zf + (long long)e * 16);
        const float4* pr = (const float4*)a.p1f;
        float s = 0.f;
#pragma unroll
        for (int qq = 0; qq < 4; qq++) {
            float4 h = zr[qq], pp = pr[qq];
            s += h.x * pp.x + h.y * pp.y + h.z * pp.z + h.w * pp.w;
        }
        float c = ep * s;
        if (ia >= 0) unsafeAtomicAdd(&a.d1[ia], a.avv[ia] * c);
        if (ib >= 0) unsafeAtomicAdd(&a.d1[ib], a.avv[ib] * c);
    } else if (b < 64) {            // edge_feat: HeW = relu(Z)@W2 ; F2 = relu(LN(Z@Wf2))
        int e = (b - 32) * 128 + t;
        const float4* zr = (const float4*)(a.Zf + (long long)e * 16);
        float zv[16];
        float4 z0 = zr[0], z1 = zr[1], z2 = zr[2], z3 = zr[3];
        zv[0] = z0.x; zv[1] = z0.y; zv[2] = z0.z; zv[3] = z0.w;
        zv[4] = z1.x; zv[5] = z1.y; zv[6] = z1.z; zv[7] = z1.w;
        zv[8] = z2.x; zv[9] = z2.y; zv[10] = z2.z; zv[11] = z2.w;
        zv[12] = z3.x; zv[13] = z3.y; zv[14] = z3.z; zv[15] = z3.w;
        float hw[16], f2[16];
#pragma unroll
        for (int c = 0; c < 16; c++) { hw[c] = 0.f; f2[c] = 0.f; }
#pragma unroll
        for (int k = 0; k < 16; k++) {
            float ar = fmaxf(zv[k], 0.f), az = zv[k];
#pragma unroll
            for (int c = 0; c < 16; c++) {
                hw[c] += ar * a.W2f[k * 16 + c];
                f2[c] += az * a.Wf2f[k * 16 + c];
            }
        }
        float m = 0.f;
#pragma unroll
        for (int c = 0; c < 16; c++) m += f2[c];
        m *= (1.f / 16.f);
        float var = 0.f;
#pragma unroll
        for (int c = 0; c < 16; c++) { float d = f2[c] - m; var += d * d; }
        var *= (1.f / 16.f);
        float rs = rsqrtf(var + 1e-5f);
#pragma unroll
        for (int c = 0; c < 16; c++)
            f2[c] = fmaxf((f2[c] - m) * rs * a.g2f[c] + a.be2f[c], 0.f);
        float4* ho = (float4*)(a.HeW + (long long)e * 16);
        ho[0] = make_float4(hw[0], hw[1], hw[2], hw[3]);
        ho[1] = make_float4(hw[4], hw[5], hw[6], hw[7]);
        ho[2] = make_float4(hw[8], hw[9], hw[10], hw[11]);
        ho[3] = make_float4(hw[12], hw[13], hw[14], hw[15]);
        float4* fo = (float4*)(a.F2 + (long long)e * 16);
        fo[0] = make_float4(f2[0], f2[1], f2[2], f2[3]);
        fo[1] = make_float4(f2[4], f2[5], f2[6], f2[7]);
        fo[2] = make_float4(f2[8], f2[9], f2[10], f2[11]);
        fo[3] = make_float4(f2[12], f2[13], f2[14], f2[15]);
    } else if (b < 2112) {          // gemm W1 (K=64)
        int i = b - 64;
        if (t < 64) arow[t] = a.Xf[(long long)i * 64 + t];
        __syncthreads();
        float acc = 0.f;
        for (int k = 0; k < 64; k++) acc += arow[k] * a.W1f[k * 128 + t];
        a.HW[(long long)i * 128 + t] = acc;
    } else {                        // gemmln Wf1 -> F1 into X1F1[:,128:]
        int i = b - 2112;
        if (t < 64) arow[t] = a.Xf[(long long)i * 64 + t];
        __syncthreads();
        float acc = 0.f;
        for (int k = 0; k < 64; k++) acc += arow[k] * a.Wf1f[k * 128 + t];
        float v = acc;
        for (int o = 32; o > 0; o >>= 1) v += __shfl_down(v, o);
        if ((t & 63) == 0) sm[t >> 6] = v;
        __syncthreads();
        float mean = (sm[0] + sm[1]) * (1.f / 128.f);
        __syncthreads();
        float d = acc - mean;
        v = d * d;
        for (int o = 32; o > 0; o >>= 1) v += __shfl_down(v, o);
        if ((t & 63) == 0) sm[t >> 6] = v;
        __syncthreads();
        float var = (sm[0] + sm[1]) * (1.f / 128.f);
        float y = d * rsqrtf(var + 1e-5f) * a.g1f[t] + a.be1f[t];
        a.X1F1[(long long)i * 256 + 128 + t] = fmaxf(y, 0.f);
    }
}

// ---- apply_node1 (delta form) + fused gate p2 -> s_n1
__global__ void __launch_bounds__(128) k_node1(GArgs a) {
    __shared__ float sm[2];
    int i = blockIdx.x, c = threadIdx.x;
    float acc = a.b1f[c];
    int n = min(a.avc[i], CAP);
    for (int s = 0; s < n; s++) {
        int idx = i * CAP + s;
        int col = a.avj[idx];
        float co = (col == i) ? a.avv[idx] : a.d1[idx];
        acc += co * a.HW[(long long)col * 128 + c];
    }
    acc = fmaxf(acc, 0.f);
    a.X1F1[(long long)i * 256 + c] = acc;
    float f = a.X1F1[(long long)i * 256 + 128 + c];
    float v = acc * a.p2f[c] + f * a.p2f[128 + c];
    for (int o = 32; o > 0; o >>= 1) v += __shfl_down(v, o);
    if ((c & 63) == 0) sm[c >> 6] = v;
    __syncthreads();
    if (c == 0) a.s_n1[i] = sm[0] + sm[1];
}

__device__ __forceinline__ void adjA_slot(const GArgs& a, int k, const float* sn,
                                          float* aea, float* colmax) {
    int e = k >> 6, s = k & 63;
    if (s >= min(a.aec[e], CAP)) return;
    int f = a.aej[k];
    float M;
    if (e == f) {
        M = 1.f;
    } else {
        M = 0.f;
        int ce = min(a.tcnt[e], 2), cf = min(a.tcnt[f], 2);
        for (int x = 0; x < ce; x++) {
            int nx = a.trows[2 * e + x]; float ux = a.tvals[2 * e + x];
            for (int y = 0; y < cf; y++)
                if (a.trows[2 * f + y] == nx) M += ux * a.tvals[2 * f + y] * sn[nx];
        }
    }
    float v = M * a.aev[k];
    aea[k] = v;
    if (v > 0.f) atomicMax((int*)&colmax[f], __float_as_int(v));
}

// ---- stage C: adjA1 | gemm W3 (K=256, 4 rows/block for weight reuse)
__global__ void __launch_bounds__(128) k_stageC(GArgs a) {
    __shared__ float lds[1024];
    int b = blockIdx.x, t = threadIdx.x;
    if (b < 2048) {
        adjA_slot(a, b * 128 + t, a.s_n1, a.aea1, a.colmax1);
    } else {
        int r0 = (b - 2048) * 4;
        for (int j = t; j < 1024; j += 128) lds[j] = a.X1F1[(long long)r0 * 256 + j];
        __syncthreads();
        float a0 = 0.f, a1 = 0.f, a2 = 0.f, a3 = 0.f;
        for (int k = 0; k < 256; k++) {
            float w = a.W3f[k * 128 + t];
            a0 += lds[k] * w; a1 += lds[256 + k] * w;
            a2 += lds[512 + k] * w; a3 += lds[768 + k] * w;
        }
        a.HW[(long long)r0 * 128 + t] = a0;
        a.HW[(long long)(r0 + 1) * 128 + t] = a1;
        a.HW[(long long)(r0 + 2) * 128 + t] = a2;
        a.HW[(long long)(r0 + 3) * 128 + t] = a3;
    }
}

// ---- edge layer 1: wave-per-edge SpMM + gate p3 + scatter d2 + fused W4 rowmat -> HeW2
__global__ void __launch_bounds__(256) k_edge1(GArgs a) {
    int e = (blockIdx.x * 256 + threadIdx.x) >> 6;
    int ln = threadIdx.x & 63;
    int sub = ln >> 4, c = ln & 15;
    float acc = 0.f;
    int n = min(a.aec[e], CAP);
    for (int s = sub; s < n; s += 4) {
        int idx = e * CAP + s;
        int f = a.aej[idx];
        float cm = a.colmax1[f];
        float nv = (cm != 0.f) ? a.aea1[idx] / cm : 0.f;
        acc += nv * a.HeW[(long long)f * 16 + c];
    }
    acc += __shfl_xor(acc, 16);
    acc += __shfl_xor(acc, 32);
    float tot = fmaxf(a.b2f[c] + acc, 0.f);         // Z2[e,c]
    float f2 = a.F2[(long long)e * 16 + c];
    // gate p3 over [Z2|F2]
    float v = tot * a.p3f[c] + f2 * a.p3f[16 + c];
#pragma unroll
    for (int m = 1; m < 16; m <<= 1) v += __shfl_xor(v, m);
    if (ln == 0) {
        float ep = a.eprod[e];
        if (ep != 0.f) {
            float cc = ep * v;
            int i1 = a.eav[2 * e], i2 = a.eav[2 * e + 1];
            if (i1 >= 0) unsafeAtomicAdd(&a.d2[i1], a.avv[i1] * cc);
            if (i2 >= 0) unsafeAtomicAdd(&a.d2[i2], a.avv[i2] * cc);
        }
    }
    // fused rowmat: HeW2[e,:] = [Z2|F2] @ W4  (in-register via shfl)
    float o = 0.f;
#pragma unroll
    for (int k = 0; k < 16; k++) {
        o += __shfl(tot, k, 16) * a.W4f[k * 16 + c];
        o += __shfl(f2, k, 16) * a.W4f[(16 + k) * 16 + c];
    }
    if (ln < 16) a.HeW2[(long long)e * 16 + c] = o;
}

// ---- apply_node3 + fused gate p4 -> s_n2
__global__ void __launch_bounds__(128) k_node3(GArgs a) {
    __shared__ float sm[2];
    int i = blockIdx.x, c = threadIdx.x;
    float acc = a.b3f[c];
    int n = min(a.avc[i], CAP);
    for (int s = 0; s < n; s++) {
        int idx = i * CAP + s;
        int col = a.avj[idx];
        float co = (col == i) ? a.avv[idx] : a.d2[idx];
        acc += co * a.HW[(long long)col * 128 + c];
    }
    acc = fmaxf(acc, 0.f);
    a.X3[(long long)i * 128 + c] = acc;
    float v = acc * a.p4f[c];
    for (int o = 32; o > 0; o >>= 1) v += __shfl_down(v, o);
    if ((c & 63) == 0) sm[c >> 6] = v;
    __syncthreads();
    if (c == 0) a.s_n2[i] = sm[0] + sm[1];
}

// ---- stage F: adjA2 | gemm W5 (K=128, 4 rows/block)
__global__ void __launch_bounds__(128) k_stageF(GArgs a) {
    __shared__ float lds[512];
    int b = blockIdx.x, t = threadIdx.x;
    if (b < 2048) {
        adjA_slot(a, b * 128 + t, a.s_n2, a.aea2, a.colmax2);
    } else {
        int r0 = (b - 2048) * 4;
        for (int j = t; j < 512; j += 128) lds[j] = a.X3[(long long)r0 * 128 + j];
        __syncthreads();
        float a0 = 0.f, a1 = 0.f, a2 = 0.f, a3 = 0.f;
        for (int k = 0; k < 128; k++) {
            float w = a.W5f[k * 128 + t];
            a0 += lds[k] * w; a1 += lds[128 + k] * w;
            a2 += lds[256 + k] * w; a3 += lds[384 + k] * w;
        }
        a.HW[(long long)r0 * 128 + t] = a0;
        a.HW[(long long)(r0 + 1) * 128 + t] = a1;
        a.HW[(long long)(r0 + 2) * 128 + t] = a2;
        a.HW[(long long)(r0 + 3) * 128 + t] = a3;
    }
}

// ---- edge layer 2: wave-per-edge SpMM + gate p5 + scatter d3 (Z4 never materialized)
__global__ void __launch_bounds__(256) k_edge2(GArgs a) {
    int e = (blockIdx.x * 256 + threadIdx.x) >> 6;
    int ln = threadIdx.x & 63;
    int sub = ln >> 4, c = ln & 15;
    float acc = 0.f;
    int n = min(a.aec[e], CAP);
    for (int s = sub; s < n; s += 4) {
        int idx = e * CAP + s;
        int f = a.aej[idx];
        float cm = a.colmax2[f];
        float nv = (cm != 0.f) ? a.aea2[idx] / cm : 0.f;
        acc += nv * a.HeW2[(long long)f * 16 + c];
    }
    acc += __shfl_xor(acc, 16);
    acc += __shfl_xor(acc, 32);
    float tot = fmaxf(a.b4f[c] + acc, 0.f);         // Z4[e,c]
    float v = tot * a.p5f[c];
#pragma unroll
    for (int m = 1; m < 16; m <<= 1) v += __shfl_xor(v, m);
    if (ln == 0) {
        float ep = a.eprod[e];
        if (ep != 0.f) {
            float cc = ep * v;
            int i1 = a.eav[2 * e], i2 = a.eav[2 * e + 1];
            if (i1 >= 0) unsafeAtomicAdd(&a.d3[i1], a.avv[i1] * cc);
            if (i2 >= 0) unsafeAtomicAdd(&a.d3[i2], a.avv[i2] * cc);
        }
    }
}

// ---- apply_node5 -> d_out
__global__ void __launch_bounds__(128) k_node5(GArgs a) {
    int i = blockIdx.x, c = threadIdx.x;
    float acc = a.b5f[c];
    int n = min(a.avc[i], CAP);
    for (int s = 0; s < n; s++) {
        int idx = i * CAP + s;
        int col = a.avj[idx];
        float co = (col == i) ? a.avv[idx] : a.d3[idx];
        acc += co * a.HW[(long long)col * 128 + c];
    }
    if (a.dt[1]) ((bf16*)a.out)[(long long)i * 128 + c] = __float2bfloat16(acc);
    else         ((float*)a.out)[(long long)i * 128 + c] = acc;
}

extern "C" void kernel_launch(void* const* d_in, const int* in_sizes, int n_in,
                              void* d_out, int out_size, void* d_ws, size_t ws_size,
                              hipStream_t stream) {
    char* wsB = (char*)d_ws;
    size_t off = 0;
    auto alloc = [&](size_t bytes) -> void* {
        void* p = wsB + off;
        off += (bytes + 255) & ~(size_t)255;
        return p;
    };
    // --- contiguous zero-init block (single memset ~1.65 MB) ---
    int*   dt      = (int*)alloc(2 * 4);
    int*   tcnt    = (int*)alloc(E_ * 4);
    int*   avc     = (int*)alloc(N_ * 4);
    int*   aec     = (int*)alloc(E_ * 4);
    float* colmax1 = (float*)alloc(E_ * 4);
    float* colmax2 = (float*)alloc(E_ * 4);
    float* d1      = (float*)alloc((size_t)N_ * CAP * 4);
    float* d2      = (float*)alloc((size_t)N_ * CAP * 4);
    float* d3      = (float*)alloc((size_t)N_ * CAP * 4);
    size_t zero_bytes = off;
    // --- converted f32 inputs ---
    float* Xf  = (float*)alloc((size_t)N_ * 64 * 4);
    float* Zf  = (float*)alloc((size_t)E_ * 16 * 4);
    float* W1f = (float*)alloc(8192 * 4);  float* p1f = (float*)alloc(16 * 4);
    float* b1f = (float*)alloc(128 * 4);
    float* Wf1f = (float*)alloc(8192 * 4); float* g1f = (float*)alloc(128 * 4);
    float* be1f = (float*)alloc(128 * 4);
    float* W2f = (float*)alloc(256 * 4);   float* p2f = (float*)alloc(256 * 4);
    float* b2f = (float*)alloc(16 * 4);
    float* Wf2f = (float*)alloc(256 * 4);  float* g2f = (float*)alloc(16 * 4);
    float* be2f = (float*)alloc(16 * 4);
    float* W3f = (float*)alloc(32768 * 4); float* p3f = (float*)alloc(32 * 4);
    float* b3f = (float*)alloc(128 * 4);
    float* W4f = (float*)alloc(512 * 4);   float* p4f = (float*)alloc(128 * 4);
    float* b4f = (float*)alloc(16 * 4);
    float* W5f = (float*)alloc(16384 * 4); float* p5f = (float*)alloc(16 * 4);
    float* b5f = (float*)alloc(128 * 4);
    // --- sparse structures + activations ---
    int*   trows  = (int*)alloc(E_ * 2 * 4);
    float* tvals  = (float*)alloc(E_ * 2 * 4);
    int*   avj    = (int*)alloc((size_t)N_ * CAP * 4);
    float* avv    = (float*)alloc((size_t)N_ * CAP * 4);
    int*   aej    = (int*)alloc((size_t)E_ * CAP * 4);
    float* aev    = (float*)alloc((size_t)E_ * CAP * 4);
    float* aea1   = (float*)alloc((size_t)E_ * CAP * 4);
    float* aea2   = (float*)alloc((size_t)E_ * CAP * 4);
    int*   eav    = (int*)alloc(E_ * 2 * 4);
    float* eprod  = (float*)alloc(E_ * 4);
    float* s_n1   = (float*)alloc(N_ * 4);
    float* s_n2   = (float*)alloc(N_ * 4);
    float* X1F1   = (float*)alloc((size_t)N_ * 256 * 4);
    float* F2b    = (float*)alloc((size_t)E_ * 16 * 4);
    float* HW     = (float*)alloc((size_t)N_ * 128 * 4);
    float* HeW    = (float*)alloc((size_t)E_ * 16 * 4);
    float* HeW2   = (float*)alloc((size_t)E_ * 16 * 4);
    float* X3     = (float*)alloc((size_t)N_ * 128 * 4);

    hipMemsetAsync(dt, 0, zero_bytes, stream);

    // 1) dtype detect (first 2 MB of T as u32)
    k_detect<<<512, 256, 0, stream>>>((const unsigned int*)d_in[4], dt + 1);

    // 2) fused extraction + upconvert
    ConvArgs ca{};
    int ne = 0;
    auto addc = [&](const void* s, float* d, int n) {
        ca.src[ne] = s; ca.dst[ne] = d; ca.n[ne] = n; ne++;
    };
    addc(d_in[0], Xf, N_ * 64);  addc(d_in[1], Zf, E_ * 16);
    addc(d_in[5], W1f, 8192);   addc(d_in[6], p1f, 16);   addc(d_in[7], b1f, 128);
    addc(d_in[8], Wf1f, 8192);  addc(d_in[9], g1f, 128);  addc(d_in[10], be1f, 128);
    addc(d_in[11], W2f, 256);   addc(d_in[12], p2f, 256); addc(d_in[13], b2f, 16);
    addc(d_in[14], Wf2f, 256);  addc(d_in[15], g2f, 16);  addc(d_in[16], be2f, 16);
    addc(d_in[17], W3f, 32768); addc(d_in[18], p3f, 32);  addc(d_in[19], b3f, 128);
    addc(d_in[20], W4f, 512);   addc(d_in[21], p4f, 128); addc(d_in[22], b4f, 16);
    addc(d_in[23], W5f, 16384); addc(d_in[24], p5f, 16);  addc(d_in[25], b5f, 128);
    int nb = 0;
    for (int e = 0; e < ne; e++) {
        ca.first[e] = nb;
        int k = (ca.n[e] + CHUNK - 1) / CHUNK;
        for (int j = 0; j < k; j++) ca.blk_entry[nb++] = (unsigned char)e;
    }

    GArgs a{d_in[4], d_in[3], d_in[2], dt,
            tcnt, trows, tvals, avc, avj, avv, aec, aej, aev,
            eav, eprod, d1, d2, d3, aea1, aea2, colmax1, colmax2,
            s_n1, s_n2, Xf, Zf,
            W1f, p1f, b1f, Wf1f, g1f, be1f,
            W2f, p2f, b2f, Wf2f, g2f, be2f,
            W3f, p3f, b3f, W4f, p4f, b4f,
            W5f, p5f, b5f,
            X1F1, F2b, HW, HeW, HeW2, X3, d_out};

    k_extract_all<<<7168 + nb, 256, 0, stream>>>(a, ca);

    // 3) pipeline: 8 stream-ordered batched dispatches
    k_stageA<<<4160, 128, 0, stream>>>(a);
    k_node1<<<N_, 128, 0, stream>>>(a);
    k_stageC<<<2560, 128, 0, stream>>>(a);
    k_edge1<<<E_ / 4, 256, 0, stream>>>(a);
    k_node3<<<N_, 128, 0, stream>>>(a);
    k_stageF<<<2560, 128, 0, stream>>>(a);
    k_edge2<<<E_ / 4, 256, 0, stream>>>(a);
    k_node5<<<N_, 128, 0, stream>>>(a);
}